// Round 1
// baseline (303.590 us; speedup 1.0000x reference)
//
#include <hip/hip_runtime.h>

// DiffIOU: BS=64 polygons of NV=128 vertices, gt_mask (BS,4,DIM,DIM), DIM=512.
// Output: scalar mean over batch of int_area/union_area.
// Strategy: 1 block per batch (128 threads = 2 waves, 1 thread/vertex),
// block reductions for y_max + 6 sums, per-batch ratio -> d_ws,
// then a 1-wave finalize kernel for the mean.

#define BS  64
#define NV  128
#define DIM 512

__device__ __forceinline__ float waveReduceSum(float v) {
#pragma unroll
    for (int off = 32; off > 0; off >>= 1) v += __shfl_down(v, off, 64);
    return v;
}

__device__ __forceinline__ float waveReduceMax(float v) {
#pragma unroll
    for (int off = 32; off > 0; off >>= 1) v = fmaxf(v, __shfl_down(v, off, 64));
    return v;
}

// 128-thread (2-wave) block reductions. sbuf has 2 floats; the leading
// __syncthreads protects sbuf reuse across consecutive calls.
__device__ __forceinline__ float blockReduceSum(float v, float* sbuf, int wave, int lane) {
    v = waveReduceSum(v);
    __syncthreads();
    if (lane == 0) sbuf[wave] = v;
    __syncthreads();
    return sbuf[0] + sbuf[1];
}

__device__ __forceinline__ float blockReduceMax(float v, float* sbuf, int wave, int lane) {
    v = waveReduceMax(v);
    __syncthreads();
    if (lane == 0) sbuf[wave] = v;
    __syncthreads();
    return fmaxf(sbuf[0], sbuf[1]);
}

__global__ __launch_bounds__(NV) void diffiou_batch_kernel(
        const float* __restrict__ pred_points,
        const float* __restrict__ gt_points,
        const float* __restrict__ gt_mask,
        float* __restrict__ ratios) {
    const int b    = blockIdx.x;
    const int v    = threadIdx.x;          // vertex 0..127
    const int vn   = (v + 1) & (NV - 1);   // roll(-1) with wrap
    const int wave = v >> 6;
    const int lane = v & 63;

    __shared__ float sbuf[2];

    const float* pp = pred_points + (size_t)b * NV * 2;
    const float* gp = gt_points   + (size_t)b * NV * 2;

    // *512 is a power-of-2 scale -> exact in f32, floors match reference
    const float px  = pp[v  * 2 + 0] * (float)DIM;
    const float py  = pp[v  * 2 + 1] * (float)DIM;
    const float pxn = pp[vn * 2 + 0] * (float)DIM;
    const float pyn = pp[vn * 2 + 1] * (float)DIM;
    const float gx  = gp[v  * 2 + 0] * (float)DIM;
    const float gy  = gp[v  * 2 + 1] * (float)DIM;
    const float gxn = gp[vn * 2 + 0] * (float)DIM;
    const float gyn = gp[vn * 2 + 1] * (float)DIM;

    // ---- polygon areas: s = sum((x1-x0)*(y_max - (y1+y0)*0.5)) ----
    const float ymax_p = blockReduceMax(py, sbuf, wave, lane);
    const float ymax_g = blockReduceMax(gy, sbuf, wave, lane);

    const float sp = blockReduceSum((pxn - px) * (ymax_p - (pyn + py) * 0.5f),
                                    sbuf, wave, lane);
    const float sg = blockReduceSum((gxn - gx) * (ymax_g - (gyn + gy) * 0.5f),
                                    sbuf, wave, lane);

    // ---- unique mask (floor-cell change) and edge signs ----
    float fx = floorf(pxn) - floorf(px);
    float fy = floorf(pyn) - floorf(py);
    if (v == 0) { fx = 1.0f; fy = 1.0f; }
    const float xm = fminf(fabsf(fx), 1.0f);
    const float ym = fminf(fabsf(fy), 1.0f);

    const float dx = pxn - px;
    const float dy = pyn - py;
    const float sx = (dx > 0.0f) ? 1.0f : ((dx < 0.0f) ? -1.0f : 0.0f);
    const float sy = (dy > 0.0f) ? 1.0f : ((dy < 0.0f) ? -1.0f : 0.0f);
    const float smx = sx * xm;
    const float smy = sy * ym;

    // ---- bilinear sample of gt_mask at (px, py), 4 channels ----
    const float X0f = floorf(px), Y0f = floorf(py);
    const float X1f = X0f + 1.0f, Y1f = Y0f + 1.0f;
    const float w00 = (X1f - px) * (Y1f - py);
    const float w01 = (X1f - px) * (py - Y0f);
    const float w10 = (px - X0f) * (Y1f - py);
    const float w11 = (px - X0f) * (py - Y0f);

    const int X0 = (int)fminf(fmaxf(X0f, 0.0f), (float)(DIM - 1));
    const int X1 = (int)fminf(fmaxf(X1f, 0.0f), (float)(DIM - 1));
    const int Y0 = (int)fminf(fmaxf(Y0f, 0.0f), (float)(DIM - 1));
    const int Y1 = (int)fminf(fmaxf(Y1f, 0.0f), (float)(DIM - 1));

    const float* mb = gt_mask + (size_t)b * 4 * DIM * DIM;
    float contrib[4];
#pragma unroll
    for (int c = 0; c < 4; ++c) {
        const float* mc  = mb + (size_t)c * DIM * DIM;
        const float M00  = mc[Y0 * DIM + X0];
        const float M01  = mc[Y1 * DIM + X0];
        const float M10  = mc[Y0 * DIM + X1];
        const float M11  = mc[Y1 * DIM + X1];
        const float interp = w00 * M00 + w01 * M01 + w10 * M10 + w11 * M11;
        contrib[c] = interp * ((c < 2) ? smx : smy);
    }

    const float S0 = blockReduceSum(contrib[0], sbuf, wave, lane);
    const float S1 = blockReduceSum(contrib[1], sbuf, wave, lane);
    const float S2 = blockReduceSum(contrib[2], sbuf, wave, lane);
    const float S3 = blockReduceSum(contrib[3], sbuf, wave, lane);

    if (v == 0) {
        const float int_area  = (fabsf(S0) + fabsf(S1) + fabsf(S2) + fabsf(S3)) * 0.25f;
        const float pred_area = fabsf(sp);
        const float gt_area   = fabsf(sg);
        const float uni       = pred_area + gt_area - int_area;
        ratios[b] = int_area / uni;
    }
}

__global__ __launch_bounds__(64) void diffiou_finalize_kernel(
        const float* __restrict__ ratios, float* __restrict__ out) {
    float v = ratios[threadIdx.x];  // 64 threads, 1 wave
    v = waveReduceSum(v);
    if (threadIdx.x == 0) out[0] = v * (1.0f / (float)BS);
}

extern "C" void kernel_launch(void* const* d_in, const int* in_sizes, int n_in,
                              void* d_out, int out_size, void* d_ws, size_t ws_size,
                              hipStream_t stream) {
    const float* pred = (const float*)d_in[0];  // (64,128,2)
    const float* gt   = (const float*)d_in[1];  // (64,128,2)
    const float* mask = (const float*)d_in[2];  // (64,4,512,512)
    float* ratios = (float*)d_ws;               // 64 floats of scratch
    float* out    = (float*)d_out;              // 1 float

    diffiou_batch_kernel<<<BS, NV, 0, stream>>>(pred, gt, mask, ratios);
    diffiou_finalize_kernel<<<1, 64, 0, stream>>>(ratios, out);
}